// Round 14
// baseline (612.860 us; speedup 1.0000x reference)
//
#include <hip/hip_runtime.h>
#include <hip/hip_bf16.h>
#include <math.h>

#define B_  32
#define T_  2048
#define D_  512
#define V_  1024
#define K_  3

typedef __attribute__((ext_vector_type(8))) short   short8;
typedef __attribute__((ext_vector_type(4))) float   floatx4;

#define SCALE_H0 256.0f        // hidden0 fp8 scale (conv1 input)
#define SCALE_A  64.0f         // H1 activation fp8 scale (conv2 input)
#define SCALE_W  16.0f         // weight fp8 scale (both convs)
#define INV1 (1.0f/(SCALE_H0*SCALE_W))
#define INV2 (1.0f/(SCALE_A*SCALE_W))

// ---- output flat offsets (elements, fp32) ----
#define OFF0 0        // global_rate      [32]
#define OFF1 32       // summary_state    [32*512]
#define OFF2 16416    // residual_mean    [32]
#define OFF3 16448    // residual_var     [32]
#define OFF4 16480    // coverage         [32]
#define OFF5 16512    // mask             [32*2048]
#define OFF6 82048    // logdur           [32*2048]
#define OFF7 147584   // ref_residual     [32*2048]
#define OFF8 213120   // attn             [32*2048]
#define OFF9 278656   // prompt_role_fit  [32*2048]
#define OFF10 344192  // coeff_norm       [32]

// ---- workspace byte offsets (total 35,553,408 B < proven 36.34 MB) ----
#define WS_RR     0          // fp32 [32][2048]              262144 B
#define WS_SUP    262144     // fp32 [32]                       128 B
#define WS_PSUM   262272     // fp32 [32][512]                65536 B
#define WS_PSUMSQ 327808     // fp32 [32][512]                65536 B
#define WS_W1P    393344     // fp8  frag-packed conv1 w     786432 B
#define WS_W2P    1179776    // fp8  frag-packed conv2 w     786432 B
#define WS_H1     1966208    // fp8  [32][2050][512]       33587200 B

__device__ __forceinline__ float clampf(float v, float lo, float hi) {
    v = (v > lo) ? v : lo;
    return (v < hi) ? v : hi;
}
// NOTE: keep gelu_exact (erff) in the conv epilogues. The inlined tanh-form
// gelu_fast triggered accumulator spill-to-scratch in R8/R9/R10 (FETCH/WRITE
// blew up 10x, conv1g 130 -> 366 us). erff's call structure keeps acc
// register-resident. Do not "optimize" this again without checking WRITE_SIZE.
__device__ __forceinline__ float gelu_exact(float v) {
    return 0.5f * v * (1.0f + erff(v * 0.70710678118654752440f));
}
__device__ __forceinline__ unsigned char f2fp8(float x) {
    int v = __builtin_amdgcn_cvt_pk_fp8_f32(x, x, 0, false);
    return (unsigned char)(v & 0xFF);
}
__device__ __forceinline__ int pk4fp8(float a, float b, float c, float d) {
    int p0 = __builtin_amdgcn_cvt_pk_fp8_f32(a, b, 0, false);
    int p1 = __builtin_amdgcn_cvt_pk_fp8_f32(c, d, 0, false);
    return (p1 << 16) | (p0 & 0xFFFF);
}

__device__ __forceinline__ float block_reduce_sum(float v, float* red, int tid) {
    __syncthreads();
    red[tid] = v;
    __syncthreads();
    for (int s = 128; s > 0; s >>= 1) {
        if (tid < s) red[tid] += red[tid + s];
        __syncthreads();
    }
    float r = red[0];
    __syncthreads();
    return r;
}

// ---------------------------------------------------------------------------
// Kernel 1: MERGED init — blocks 0..31: per-batch stats (histogram-select
//   exact median + T-wise outputs); blocks 32..63: LDS-transpose weight
//   prepack (coalesced fp32 reads -> fp8 LDS -> coalesced 512B packed writes)
//   + psum/H1-pad zeroing.
//  Packed layout (R7): double idx = (s*32+ntg)*64+lane holds w[col][kin+e][k],
//    s = k*16+ci, col = ntg*16+(lane&15), kin = ci*32+(lane>>4)*8
// ---------------------------------------------------------------------------
#define NB 2048
#define HLO (-9.3f)
#define HSC ((float)NB / 10.05f)     // range [-9.3, 0.75]
#define WLS 1544                     // LDS row stride (1536 + 8 pad)
__global__ __launch_bounds__(256) void init_kernel(
    const float* __restrict__ dur, const float* __restrict__ maskp,
    const float* __restrict__ w1, const float* __restrict__ w2,
    unsigned char* __restrict__ W1p, unsigned char* __restrict__ W2p,
    unsigned char* __restrict__ H1buf,
    float* __restrict__ rr_ws, float* __restrict__ sup_ws,
    float* __restrict__ psum, float* __restrict__ out)
{
    int tid = threadIdx.x;

    if (blockIdx.x >= 32) {
        // ---------------- prepack part (LDS transpose) ----------------
        __shared__ unsigned char Wl[2 * 16 * WLS];   // 49408 B
        int ntg = blockIdx.x - 32;                   // 0..31 (16-col group)
        int lane = tid & 63, wave = tid >> 6;

        #pragma unroll
        for (int ws = 0; ws < 2; ++ws) {
            const float* wsrc = (ws ? w2 : w1) + (size_t)ntg * 16 * 1536;
            for (int i = tid; i < 6144; i += 256) {      // 16 cols x 1536 f
                float4 v = ((const float4*)wsrc)[i];
                int col_local = i / 384;                 // 384 float4 per col
                int pos = (i % 384) * 4;
                int word = pk4fp8(v.x * SCALE_W, v.y * SCALE_W,
                                  v.z * SCALE_W, v.w * SCALE_W);
                *(int*)(&Wl[(ws * 16 + col_local) * WLS + pos]) = word;
            }
        }
        __syncthreads();

        int cl = lane & 15, qq = lane >> 4;
        #pragma unroll
        for (int ws = 0; ws < 2; ++ws) {
            unsigned char* dst = ws ? W2p : W1p;
            for (int s = wave; s < 48; s += 4) {
                int ci = s & 15, k = s >> 4;
                const unsigned char* row = &Wl[(ws * 16 + cl) * WLS];
                int kin = ci * 32 + qq * 8;
                unsigned char bb[8];
                #pragma unroll
                for (int e = 0; e < 8; ++e)
                    bb[e] = row[(kin + e) * 3 + k];
                *(double*)(dst + ((size_t)(s * 32 + ntg) * 64 + lane) * 8) =
                    *(double*)bb;
            }
        }

        // zeroing: 32 blocks x 256 threads x 4 = 32768 elems each array
        int pid2 = ntg * 256 + tid;
        #pragma unroll
        for (int j = 0; j < 4; ++j) {
            int idx = pid2 + j * 8192;
            psum[idx] = 0.0f;                      // psum + psumsq contiguous
            int b = idx >> 10;
            int r = (idx >> 9) & 1;
            int d = idx & 511;
            H1buf[((size_t)b * 2050 + r) * 512 + d] = 0;
        }
        return;
    }

    // ---------------- stats part ----------------
    __shared__ int   hist[NB];
    __shared__ int   csum[256];
    __shared__ float red[256];
    __shared__ float cand[128];
    __shared__ float nsh, medsh;
    __shared__ int   sh_tb, sh_cb, sh_candn;

    int b = blockIdx.x;
    const float* durb = dur + (size_t)b * T_;
    const float* mkb  = maskp + (size_t)b * T_;

    float ld[8], mk[8];
    int   bn[8];
    float cnt = 0.0f;
    #pragma unroll
    for (int i = 0; i < 8; ++i) hist[tid * 8 + i] = 0;
    __syncthreads();
    #pragma unroll
    for (int i = 0; i < 8; ++i) {
        int t = tid + i * 256;
        float m = clampf(mkb[t], 0.0f, 1.0f);
        float dv = durb[t];
        dv = (dv >= 1e-4f) ? dv : 1e-4f;
        float l = logf(dv) * m;
        ld[i] = l; mk[i] = m;
        int bin = (int)((l - HLO) * HSC);
        bin = (bin < 0) ? 0 : ((bin > NB - 1) ? NB - 1 : bin);
        bn[i] = bin;
        if (m > 0.5f) { cnt += 1.0f; atomicAdd(&hist[bin], 1); }
    }
    float n = block_reduce_sum(cnt, red, tid);   // barriers make hist visible
    if (tid == 0) { nsh = n; sh_candn = 0; medsh = 0.0f; }

    // chunk sums + inclusive scan (Hillis-Steele)
    {
        int cs = 0;
        #pragma unroll
        for (int i = 0; i < 8; ++i) cs += hist[tid * 8 + i];
        csum[tid] = cs;
        __syncthreads();
        for (int off = 1; off < 256; off <<= 1) {
            int v = (tid >= off) ? csum[tid - off] : 0;
            __syncthreads();
            csum[tid] += v;
            __syncthreads();
        }
    }
    int ni = (int)(n + 0.5f);
    int k  = (ni > 0) ? ((ni - 1) >> 1) : 0;     // 0-indexed lower-median rank
    {
        int prevIncl = (tid > 0) ? csum[tid - 1] : 0;
        if (ni > 0 && k >= prevIncl && k < csum[tid]) {   // unique owner thread
            int cum = prevIncl, tb = tid * 8;
            #pragma unroll
            for (int i = 0; i < 8; ++i) {
                int c = hist[tid * 8 + i];
                if (k < cum + c) { tb = tid * 8 + i; break; }
                cum += c;
            }
            sh_tb = tb; sh_cb = cum;
        }
    }
    __syncthreads();
    // collect candidates in target bin
    if (ni > 0) {
        int tb = sh_tb;
        #pragma unroll
        for (int i = 0; i < 8; ++i) {
            if (mk[i] > 0.5f && bn[i] == tb) {
                int p = atomicAdd(&sh_candn, 1);
                if (p < 128) cand[p] = ld[i];
            }
        }
    }
    __syncthreads();
    if (tid == 0 && ni > 0) {
        int m = k - sh_cb;
        int cn = (sh_candn < 128) ? sh_candn : 128;
        float best = cand[0];
        for (int i = 0; i < cn; ++i) {
            int rank = 0;
            for (int j = 0; j < cn; ++j)
                rank += (cand[j] < cand[i]) || (cand[j] == cand[i] && j < i);
            if (rank == m) { best = cand[i]; break; }
        }
        medsh = best;
    }
    __syncthreads();
    float med = (ni > 0) ? medsh : 0.0f;
    med = clampf(med, -20.0f, 20.0f);

    float denom = (n > 1.0f) ? n : 1.0f;
    float rv[8];
    float ssum = 0.0f;
    #pragma unroll
    for (int i = 0; i < 8; ++i) { rv[i] = (ld[i] - med) * mk[i]; ssum += rv[i]; }
    float rsum = block_reduce_sum(ssum, red, tid);
    float rm = clampf(rsum / denom, -40.0f, 40.0f);

    float vsum_l = 0.0f;
    #pragma unroll
    for (int i = 0; i < 8; ++i) { float dd = rv[i] - rm; vsum_l += dd * dd * mk[i]; }
    float vsum = block_reduce_sum(vsum_l, red, tid);
    float var = clampf(vsum / denom, 1e-4f, 1e4f);

    float inv_sup = 1.0f / denom;
    #pragma unroll
    for (int i = 0; i < 8; ++i) {
        int t = tid + i * 256;
        size_t o = (size_t)b * T_ + t;
        out[OFF5 + o] = mk[i];
        out[OFF6 + o] = ld[i];
        out[OFF7 + o] = rv[i];
        out[OFF8 + o] = mk[i] * inv_sup;
        out[OFF9 + o] = rm * mk[i];
        rr_ws[o] = rv[i];
    }
    if (tid == 0) {
        out[OFF0 + b] = med;
        out[OFF2 + b] = rm;
        out[OFF3 + b] = var;
        float cov = n * (1.0f / (float)T_);
        out[OFF4 + b] = (cov > 0.05f) ? cov : 0.05f;
        sup_ws[b] = n;
    }
}

// ---------------------------------------------------------------------------
// Kernel 2: conv1 gather-GEMM, fp8 MFMA. BM=64 x 512 (two 256-col halves,
//   acc[4][4]). Strided fragment loads (4 x 8 B/step, depth-1 prefetch).
//   launch_bounds MUST stay (256,3): (256,4) forces a 64-VGPR allocation
//   on this compiler (measured twice: R8, R12) -> accumulator spill ->
//   100+ MB scratch WRITE_SIZE, 2x slower. (256,3) = 76 VGPR, no scratch.
// ---------------------------------------------------------------------------
#define H0S 520
__global__ __launch_bounds__(256, 3) void conv1g_kernel(
    const int* __restrict__ ids, const float* __restrict__ rr,
    const float* __restrict__ emb,
    const float* __restrict__ aux_w, const float* __restrict__ aux_b,
    const unsigned char* __restrict__ W1p, const float* __restrict__ bias1,
    unsigned char* __restrict__ H1buf)
{
    __shared__ __align__(16) unsigned char H0s[66 * H0S];   // 34320 B
    __shared__ int   lid[66];
    __shared__ float lrr[66];

    int tile = blockIdx.x;          // 0..31
    int b    = blockIdx.y;          // 0..31
    int r0   = tile << 6;
    int tid  = threadIdx.x;
    int wave = tid >> 6, lane = tid & 63;
    int q = lane >> 4, m16 = lane & 15;

    if (tid < 66) {
        int t = r0 - 2 + tid;
        bool v = (t >= 0);
        lid[tid] = v ? ids[b * T_ + t] : -1;
        lrr[tid] = v ? rr[(size_t)b * T_ + t] : 0.0f;
    }
    __syncthreads();

    {   // gather hidden0 -> fp8 LDS
        int c4 = tid & 127;
        float4 aw = *(const float4*)(aux_w + c4 * 4);
        float4 ab = *(const float4*)(aux_b + c4 * 4);
        int rbase = tid >> 7;
        for (int j = 0; j < 33; ++j) {
            int row = rbase + j * 2;
            int id = lid[row];
            int word = 0;
            if (id >= 0) {
                float vr = lrr[row];
                float4 e = *(const float4*)(emb + (size_t)id * D_ + c4 * 4);
                word = pk4fp8((e.x + vr * aw.x + ab.x) * SCALE_H0,
                              (e.y + vr * aw.y + ab.y) * SCALE_H0,
                              (e.z + vr * aw.z + ab.z) * SCALE_H0,
                              (e.w + vr * aw.w + ab.w) * SCALE_H0);
            }
            *(int*)(&H0s[row * H0S + c4 * 4]) = word;
        }
    }
    __syncthreads();

    unsigned char* Ob = H1buf + ((size_t)b * 2050 + 2 + r0) * 512;

    #pragma unroll
    for (int nh = 0; nh < 2; ++nh) {
        floatx4 acc[4][4];
        #pragma unroll
        for (int i = 0; i < 4; ++i)
            #pragma unroll
            for (int j = 0; j < 4; ++j)
                acc[i][j] = (floatx4){0.f, 0.f, 0.f, 0.f};

        const long* wp[4];
        #pragma unroll
        for (int nt = 0; nt < 4; ++nt) {
            int ntg = nh * 16 + wave * 4 + nt;
            wp[nt] = (const long*)W1p + ((size_t)ntg * 64 + lane);
        }
        long bfr[2][4];
        #pragma unroll
        for (int nt = 0; nt < 4; ++nt) bfr[0][nt] = wp[nt][0];

        for (int s = 0; s < 48; ++s) {
            int cur = s & 1;
            if (s + 1 < 48) {
                #pragma unroll
                for (int nt = 0; nt < 4; ++nt)
                    bfr[cur ^ 1][nt] = wp[nt][(size_t)(s + 1) * 2048]; // 32*64 longs
            }
            int k1 = s >> 4, ci = s & 15;
            #pragma unroll
            for (int mt = 0; mt < 4; ++mt) {
                long afr = *(const long*)(&H0s[(mt * 16 + m16 + k1) * H0S + ci * 32 + q * 8]);
                #pragma unroll
                for (int nt = 0; nt < 4; ++nt)
                    acc[mt][nt] = __builtin_amdgcn_mfma_f32_16x16x32_fp8_fp8(
                        afr, bfr[cur][nt], acc[mt][nt], 0, 0, 0);
            }
        }

        #pragma unroll
        for (int mt = 0; mt < 4; ++mt) {
            #pragma unroll
            for (int nt = 0; nt < 4; ++nt) {
                int col = nh * 256 + wave * 64 + nt * 16 + m16;
                float bsv = bias1[col];
                #pragma unroll
                for (int r = 0; r < 4; ++r) {
                    int row = mt * 16 + q * 4 + r;
                    float v = gelu_exact(acc[mt][nt][r] * INV1 + bsv) * SCALE_A;
                    Ob[(size_t)row * 512 + col] = f2fp8(v);
                }
            }
        }
    }
}

// ---------------------------------------------------------------------------
// Kernel 3: conv2 (fp8 MFMA) + gelu + LN + masked column sums.
//   BM=32 x full 512 cols (acc[2][8] = 64 regs), LN from live accumulators.
//   R14: depth-1 prefetch of the 8 weight fragments restored (R13 had none —
//   each step serialized on L2 latency, 151 us at MfmaUtil 29%).
//   TRIPWIRE: WRITE_SIZE >> 8 MB => spill => revert prefetch.
// ---------------------------------------------------------------------------
#define H1S 520
__global__ __launch_bounds__(256, 2) void conv2ln_kernel(
    const unsigned char* __restrict__ H1buf, const unsigned char* __restrict__ W2p,
    const float* __restrict__ bias2,
    const float* __restrict__ ln_g, const float* __restrict__ ln_b,
    const float* __restrict__ maskp,
    float* __restrict__ psum, float* __restrict__ psumsq)
{
    __shared__ __align__(16) unsigned char H1s[34 * H1S];   // 17680 B
    __shared__ float mrow[32];
    __shared__ float part[32][4][2];
    __shared__ float tot[32][2];
    __shared__ float colsum[512][2];

    int tile = blockIdx.x;          // 0..63
    int b    = blockIdx.y;          // 0..31
    int r0   = tile << 5;           // output rows r0..r0+31
    int tid  = threadIdx.x;
    int wave = tid >> 6, lane = tid & 63;
    int q = lane >> 4, m16 = lane & 15;
    int nbase = wave << 7;

    const unsigned char* src = H1buf + ((size_t)b * 2050 + r0) * 512;
    for (int g = tid; g < 34 * 32; g += 256) {
        int row = g >> 5, h = g & 31;
        *(float4*)(&H1s[row * H1S + h * 16]) = *(const float4*)(src + (size_t)row * 512 + h * 16);
    }
    if (tid < 32)
        mrow[tid] = clampf(maskp[(size_t)b * T_ + r0 + tid], 0.0f, 1.0f);
    __syncthreads();

    floatx4 acc[2][8];
    #pragma unroll
    for (int i = 0; i < 2; ++i)
        #pragma unroll
        for (int j = 0; j < 8; ++j)
            acc[i][j] = (floatx4){0.f, 0.f, 0.f, 0.f};

    // fragment (s,nt) at wbase[s*2048 + nt*64]; nt*64 longs = 512 B -> imm offs
    const long* wbase = (const long*)W2p + ((size_t)(wave * 8) * 64 + lane);
    long bfr[2][8];
    #pragma unroll
    for (int nt = 0; nt < 8; ++nt) bfr[0][nt] = wbase[nt * 64];

    for (int s = 0; s < 48; ++s) {
        int cur = s & 1;
        if (s + 1 < 48) {
            const long* wn = wbase + (size_t)(s + 1) * 2048;
            #pragma unroll
            for (int nt = 0; nt < 8; ++nt) bfr[cur ^ 1][nt] = wn[nt * 64];
        }
        int k2 = s >> 4, ci = s & 15;
        #pragma unroll
        for (int mt = 0; mt < 2; ++mt) {
            long afr = *(const long*)(&H1s[(mt * 16 + m16 + k2) * H1S + ci * 32 + q * 8]);
            #pragma unroll
            for (int nt = 0; nt < 8; ++nt)
                acc[mt][nt] = __builtin_amdgcn_mfma_f32_16x16x32_fp8_fp8(
                    afr, bfr[cur][nt], acc[mt][nt], 0, 0, 0);
        }
    }

    // epilogue: descale + bias + gelu
    #pragma unroll
    for (int mt = 0; mt < 2; ++mt)
        #pragma unroll
        for (int nt = 0; nt < 8; ++nt) {
            int col = nbase + nt * 16 + m16;
            float bsv = bias2[col];
            #pragma unroll
            for (int r = 0; r < 4; ++r)
                acc[mt][nt][r] = gelu_exact(acc[mt][nt][r] * INV2 + bsv);
        }

    // LN row stats
    #pragma unroll
    for (int mt = 0; mt < 2; ++mt) {
        #pragma unroll
        for (int r = 0; r < 4; ++r) {
            float rs = 0.f, rq = 0.f;
            #pragma unroll
            for (int nt = 0; nt < 8; ++nt) {
                float v = acc[mt][nt][r];
                rs += v; rq += v * v;
            }
            rs += __shfl_xor(rs, 1);  rq += __shfl_xor(rq, 1);
            rs += __shfl_xor(rs, 2);  rq += __shfl_xor(rq, 2);
            rs += __shfl_xor(rs, 4);  rq += __shfl_xor(rq, 4);
            rs += __shfl_xor(rs, 8);  rq += __shfl_xor(rq, 8);
            if (m16 == 0) {
                int row = mt * 16 + q * 4 + r;
                part[row][wave][0] = rs;
                part[row][wave][1] = rq;
            }
        }
    }
    __syncthreads();
    if (tid < 64) {
        int row = tid >> 1, j = tid & 1;
        tot[row][j] = part[row][0][j] + part[row][1][j] + part[row][2][j] + part[row][3][j];
    }
    __syncthreads();

    float meanv[2][4], rstdv[2][4];
    #pragma unroll
    for (int mt = 0; mt < 2; ++mt)
        #pragma unroll
        for (int r = 0; r < 4; ++r) {
            int row = mt * 16 + q * 4 + r;
            float m = tot[row][0] * (1.0f / D_);
            float var = tot[row][1] * (1.0f / D_) - m * m;
            meanv[mt][r] = m;
            rstdv[mt][r] = rsqrtf((var > 0.0f ? var : 0.0f) + 1e-5f);
        }

    float cs[8], cq[8];
    #pragma unroll
    for (int nt = 0; nt < 8; ++nt) { cs[nt] = 0.f; cq[nt] = 0.f; }
    #pragma unroll
    for (int mt = 0; mt < 2; ++mt) {
        #pragma unroll
        for (int r = 0; r < 4; ++r) {
            int row = mt * 16 + q * 4 + r;
            float mk = mrow[row];
            float m = meanv[mt][r], rs = rstdv[mt][r];
            #pragma unroll
            for (int nt = 0; nt < 8; ++nt) {
                int col = nbase + nt * 16 + m16;
                float xn = ((acc[mt][nt][r] - m) * rs * ln_g[col] + ln_b[col]) * mk;
                cs[nt] += xn;
                cq[nt] += xn * xn;
            }
        }
    }
    #pragma unroll
    for (int nt = 0; nt < 8; ++nt) {
        cs[nt] += __shfl_xor(cs[nt], 16);  cq[nt] += __shfl_xor(cq[nt], 16);
        cs[nt] += __shfl_xor(cs[nt], 32);  cq[nt] += __shfl_xor(cq[nt], 32);
    }
    if (lane < 16) {
        #pragma unroll
        for (int nt = 0; nt < 8; ++nt) {
            int col = nbase + nt * 16 + m16;
            colsum[col][0] = cs[nt];
            colsum[col][1] = cq[nt];
        }
    }
    __syncthreads();
    for (int i = tid; i < 512; i += 256) {
        atomicAdd(&psum[(size_t)b * D_ + i], colsum[i][0]);
        atomicAdd(&psumsq[(size_t)b * D_ + i], colsum[i][1]);
    }
}

// ---------------------------------------------------------------------------
// Kernel 4: per-batch MLP head: mean/std -> p1/gelu -> p2/tanh, coeff_norm
// ---------------------------------------------------------------------------
__global__ __launch_bounds__(512) void mlp_kernel(
    const float* __restrict__ psum, const float* __restrict__ psumsq,
    const float* __restrict__ sup_ws,
    const float* __restrict__ p1w, const float* __restrict__ p1b,
    const float* __restrict__ p2w, const float* __restrict__ p2b,
    float* __restrict__ out)
{
    int b = blockIdx.x;
    int d = threadIdx.x;
    __shared__ float h[2 * D_];
    __shared__ float s1[D_];
    __shared__ float red[512];

    float n = sup_ws[b];
    float denom = (n > 1.0f) ? n : 1.0f;
    float S = psum[(size_t)b * D_ + d];
    float Q = psumsq[(size_t)b * D_ + d];
    float mean = S / denom;
    float msum = Q - 2.0f * mean * S + n * mean * mean;
    float arg = msum / denom + 1e-6f;
    float sd = sqrtf((arg > 0.0f) ? arg : 0.0f);
    h[d] = mean;
    h[D_ + d] = sd;
    __syncthreads();

    float z = p1b[d];
    const float4* w4 = (const float4*)(p1w + (size_t)d * (2 * D_));
    for (int jj = 0; jj < 2 * D_ / 4; ++jj) {
        float4 wv = w4[jj];
        z += h[jj * 4 + 0] * wv.x + h[jj * 4 + 1] * wv.y
           + h[jj * 4 + 2] * wv.z + h[jj * 4 + 3] * wv.w;
    }
    s1[d] = gelu_exact(z);
    __syncthreads();

    float z2 = p2b[d];
    const float4* w24 = (const float4*)(p2w + (size_t)d * D_);
    for (int jj = 0; jj < D_ / 4; ++jj) {
        float4 wv = w24[jj];
        z2 += s1[jj * 4 + 0] * wv.x + s1[jj * 4 + 1] * wv.y
            + s1[jj * 4 + 2] * wv.z + s1[jj * 4 + 3] * wv.w;
    }
    float st = tanhf(z2);
    if (!(n > 0.0f)) st = 0.0f;
    out[OFF1 + (size_t)b * D_ + d] = st;

    red[d] = st * st;
    __syncthreads();
    for (int s = 256; s > 0; s >>= 1) {
        if (d < s) red[d] += red[d + s];
        __syncthreads();
    }
    if (d == 0) out[OFF10 + b] = sqrtf(red[0]);
}

// ---------------------------------------------------------------------------
extern "C" void kernel_launch(void* const* d_in, const int* in_sizes, int n_in,
                              void* d_out, int out_size, void* d_ws, size_t ws_size,
                              hipStream_t stream) {
    (void)in_sizes; (void)n_in; (void)out_size; (void)ws_size;
    const int*   unit_ids = (const int*)d_in[0];
    const float* dur      = (const float*)d_in[1];
    const float* mask     = (const float*)d_in[2];
    const float* emb      = (const float*)d_in[3];
    const float* aux_w    = (const float*)d_in[4];
    const float* aux_b    = (const float*)d_in[5];
    const float* conv1_w  = (const float*)d_in[6];
    const float* conv1_b  = (const float*)d_in[7];
    const float* conv2_w  = (const float*)d_in[8];
    const float* conv2_b  = (const float*)d_in[9];
    const float* ln_g     = (const float*)d_in[10];
    const float* ln_b     = (const float*)d_in[11];
    const float* p1_w     = (const float*)d_in[12];
    const float* p1_b     = (const float*)d_in[13];
    const float* p2_w     = (const float*)d_in[14];
    const float* p2_b     = (const float*)d_in[15];
    float* out = (float*)d_out;

    char* ws = (char*)d_ws;
    float*          rr     = (float*)(ws + WS_RR);
    float*          sup    = (float*)(ws + WS_SUP);
    float*          psum   = (float*)(ws + WS_PSUM);
    float*          psumsq = (float*)(ws + WS_PSUMSQ);
    unsigned char*  W1p    = (unsigned char*)(ws + WS_W1P);
    unsigned char*  W2p    = (unsigned char*)(ws + WS_W2P);
    unsigned char*  H1buf  = (unsigned char*)(ws + WS_H1);

    init_kernel<<<dim3(64), dim3(256), 0, stream>>>(
        dur, mask, conv1_w, conv2_w, W1p, W2p, H1buf, rr, sup, psum, out);
    conv1g_kernel<<<dim3(32, 32), dim3(256), 0, stream>>>(
        unit_ids, rr, emb, aux_w, aux_b, W1p, conv1_b, H1buf);
    conv2ln_kernel<<<dim3(64, 32), dim3(256), 0, stream>>>(
        H1buf, W2p, conv2_b, ln_g, ln_b, mask, psum, psumsq);
    mlp_kernel<<<dim3(B_), dim3(512), 0, stream>>>(
        psum, psumsq, sup, p1_w, p1_b, p2_w, p2_b, out);
}

// Round 15
// 435.252 us; speedup vs baseline: 1.4081x; 1.4081x over previous
//
#include <hip/hip_runtime.h>
#include <hip/hip_bf16.h>
#include <math.h>

#define B_  32
#define T_  2048
#define D_  512
#define V_  1024
#define K_  3

typedef __attribute__((ext_vector_type(8))) short   short8;
typedef __attribute__((ext_vector_type(4))) float   floatx4;

#define SCALE_H0 256.0f        // hidden0 fp8 scale (conv1 input)
#define SCALE_A  64.0f         // H1 activation fp8 scale (conv2 input)
#define SCALE_W  16.0f         // weight fp8 scale (both convs)
#define INV1 (1.0f/(SCALE_H0*SCALE_W))
#define INV2 (1.0f/(SCALE_A*SCALE_W))

// ---- output flat offsets (elements, fp32) ----
#define OFF0 0        // global_rate      [32]
#define OFF1 32       // summary_state    [32*512]
#define OFF2 16416    // residual_mean    [32]
#define OFF3 16448    // residual_var     [32]
#define OFF4 16480    // coverage         [32]
#define OFF5 16512    // mask             [32*2048]
#define OFF6 82048    // logdur           [32*2048]
#define OFF7 147584   // ref_residual     [32*2048]
#define OFF8 213120   // attn             [32*2048]
#define OFF9 278656   // prompt_role_fit  [32*2048]
#define OFF10 344192  // coeff_norm       [32]

// ---- workspace byte offsets (total 35,553,408 B < proven 36.34 MB) ----
#define WS_RR     0          // fp32 [32][2048]              262144 B
#define WS_SUP    262144     // fp32 [32]                       128 B
#define WS_PSUM   262272     // fp32 [32][512]                65536 B
#define WS_PSUMSQ 327808     // fp32 [32][512]                65536 B
#define WS_W1P    393344     // fp8  frag-packed conv1 w     786432 B
#define WS_W2P    1179776    // fp8  frag-packed conv2 w     786432 B
#define WS_H1     1966208    // fp8  [32][2050][512]       33587200 B

__device__ __forceinline__ float clampf(float v, float lo, float hi) {
    v = (v > lo) ? v : lo;
    return (v < hi) ? v : hi;
}
// NOTE: keep gelu_exact (erff) in the conv epilogues. The inlined tanh-form
// gelu_fast triggered accumulator spill-to-scratch in R8/R9/R10 (FETCH/WRITE
// blew up 10x, conv1g 130 -> 366 us). erff's call structure keeps acc
// register-resident. Do not "optimize" this again without checking WRITE_SIZE.
__device__ __forceinline__ float gelu_exact(float v) {
    return 0.5f * v * (1.0f + erff(v * 0.70710678118654752440f));
}
__device__ __forceinline__ unsigned char f2fp8(float x) {
    int v = __builtin_amdgcn_cvt_pk_fp8_f32(x, x, 0, false);
    return (unsigned char)(v & 0xFF);
}
__device__ __forceinline__ int pk4fp8(float a, float b, float c, float d) {
    int p0 = __builtin_amdgcn_cvt_pk_fp8_f32(a, b, 0, false);
    int p1 = __builtin_amdgcn_cvt_pk_fp8_f32(c, d, 0, false);
    return (p1 << 16) | (p0 & 0xFFFF);
}

__device__ __forceinline__ float block_reduce_sum(float v, float* red, int tid) {
    __syncthreads();
    red[tid] = v;
    __syncthreads();
    for (int s = 128; s > 0; s >>= 1) {
        if (tid < s) red[tid] += red[tid + s];
        __syncthreads();
    }
    float r = red[0];
    __syncthreads();
    return r;
}

// ---------------------------------------------------------------------------
// Kernel 1: MERGED init — blocks 0..31: per-batch stats (histogram-select
//   exact median + T-wise outputs); blocks 32..63: LDS-transpose weight
//   prepack (coalesced fp32 reads -> fp8 LDS -> coalesced 512B packed writes)
//   + psum/H1-pad zeroing.
//  Packed layout (R7): double idx = (s*32+ntg)*64+lane holds w[col][kin+e][k],
//    s = k*16+ci, col = ntg*16+(lane&15), kin = ci*32+(lane>>4)*8
// ---------------------------------------------------------------------------
#define NB 2048
#define HLO (-9.3f)
#define HSC ((float)NB / 10.05f)     // range [-9.3, 0.75]
#define WLS 1544                     // LDS row stride (1536 + 8 pad)
__global__ __launch_bounds__(256) void init_kernel(
    const float* __restrict__ dur, const float* __restrict__ maskp,
    const float* __restrict__ w1, const float* __restrict__ w2,
    unsigned char* __restrict__ W1p, unsigned char* __restrict__ W2p,
    unsigned char* __restrict__ H1buf,
    float* __restrict__ rr_ws, float* __restrict__ sup_ws,
    float* __restrict__ psum, float* __restrict__ out)
{
    int tid = threadIdx.x;

    if (blockIdx.x >= 32) {
        // ---------------- prepack part (LDS transpose) ----------------
        __shared__ unsigned char Wl[2 * 16 * WLS];   // 49408 B
        int ntg = blockIdx.x - 32;                   // 0..31 (16-col group)
        int lane = tid & 63, wave = tid >> 6;

        #pragma unroll
        for (int ws = 0; ws < 2; ++ws) {
            const float* wsrc = (ws ? w2 : w1) + (size_t)ntg * 16 * 1536;
            for (int i = tid; i < 6144; i += 256) {      // 16 cols x 1536 f
                float4 v = ((const float4*)wsrc)[i];
                int col_local = i / 384;                 // 384 float4 per col
                int pos = (i % 384) * 4;
                int word = pk4fp8(v.x * SCALE_W, v.y * SCALE_W,
                                  v.z * SCALE_W, v.w * SCALE_W);
                *(int*)(&Wl[(ws * 16 + col_local) * WLS + pos]) = word;
            }
        }
        __syncthreads();

        int cl = lane & 15, qq = lane >> 4;
        #pragma unroll
        for (int ws = 0; ws < 2; ++ws) {
            unsigned char* dst = ws ? W2p : W1p;
            for (int s = wave; s < 48; s += 4) {
                int ci = s & 15, k = s >> 4;
                const unsigned char* row = &Wl[(ws * 16 + cl) * WLS];
                int kin = ci * 32 + qq * 8;
                unsigned char bb[8];
                #pragma unroll
                for (int e = 0; e < 8; ++e)
                    bb[e] = row[(kin + e) * 3 + k];
                *(double*)(dst + ((size_t)(s * 32 + ntg) * 64 + lane) * 8) =
                    *(double*)bb;
            }
        }

        // zeroing: 32 blocks x 256 threads x 4 = 32768 elems each array
        int pid2 = ntg * 256 + tid;
        #pragma unroll
        for (int j = 0; j < 4; ++j) {
            int idx = pid2 + j * 8192;
            psum[idx] = 0.0f;                      // psum + psumsq contiguous
            int b = idx >> 10;
            int r = (idx >> 9) & 1;
            int d = idx & 511;
            H1buf[((size_t)b * 2050 + r) * 512 + d] = 0;
        }
        return;
    }

    // ---------------- stats part ----------------
    __shared__ int   hist[NB];
    __shared__ int   csum[256];
    __shared__ float red[256];
    __shared__ float cand[128];
    __shared__ float nsh, medsh;
    __shared__ int   sh_tb, sh_cb, sh_candn;

    int b = blockIdx.x;
    const float* durb = dur + (size_t)b * T_;
    const float* mkb  = maskp + (size_t)b * T_;

    float ld[8], mk[8];
    int   bn[8];
    float cnt = 0.0f;
    #pragma unroll
    for (int i = 0; i < 8; ++i) hist[tid * 8 + i] = 0;
    __syncthreads();
    #pragma unroll
    for (int i = 0; i < 8; ++i) {
        int t = tid + i * 256;
        float m = clampf(mkb[t], 0.0f, 1.0f);
        float dv = durb[t];
        dv = (dv >= 1e-4f) ? dv : 1e-4f;
        float l = logf(dv) * m;
        ld[i] = l; mk[i] = m;
        int bin = (int)((l - HLO) * HSC);
        bin = (bin < 0) ? 0 : ((bin > NB - 1) ? NB - 1 : bin);
        bn[i] = bin;
        if (m > 0.5f) { cnt += 1.0f; atomicAdd(&hist[bin], 1); }
    }
    float n = block_reduce_sum(cnt, red, tid);   // barriers make hist visible
    if (tid == 0) { nsh = n; sh_candn = 0; medsh = 0.0f; }

    // chunk sums + inclusive scan (Hillis-Steele)
    {
        int cs = 0;
        #pragma unroll
        for (int i = 0; i < 8; ++i) cs += hist[tid * 8 + i];
        csum[tid] = cs;
        __syncthreads();
        for (int off = 1; off < 256; off <<= 1) {
            int v = (tid >= off) ? csum[tid - off] : 0;
            __syncthreads();
            csum[tid] += v;
            __syncthreads();
        }
    }
    int ni = (int)(n + 0.5f);
    int k  = (ni > 0) ? ((ni - 1) >> 1) : 0;     // 0-indexed lower-median rank
    {
        int prevIncl = (tid > 0) ? csum[tid - 1] : 0;
        if (ni > 0 && k >= prevIncl && k < csum[tid]) {   // unique owner thread
            int cum = prevIncl, tb = tid * 8;
            #pragma unroll
            for (int i = 0; i < 8; ++i) {
                int c = hist[tid * 8 + i];
                if (k < cum + c) { tb = tid * 8 + i; break; }
                cum += c;
            }
            sh_tb = tb; sh_cb = cum;
        }
    }
    __syncthreads();
    // collect candidates in target bin
    if (ni > 0) {
        int tb = sh_tb;
        #pragma unroll
        for (int i = 0; i < 8; ++i) {
            if (mk[i] > 0.5f && bn[i] == tb) {
                int p = atomicAdd(&sh_candn, 1);
                if (p < 128) cand[p] = ld[i];
            }
        }
    }
    __syncthreads();
    if (tid == 0 && ni > 0) {
        int m = k - sh_cb;
        int cn = (sh_candn < 128) ? sh_candn : 128;
        float best = cand[0];
        for (int i = 0; i < cn; ++i) {
            int rank = 0;
            for (int j = 0; j < cn; ++j)
                rank += (cand[j] < cand[i]) || (cand[j] == cand[i] && j < i);
            if (rank == m) { best = cand[i]; break; }
        }
        medsh = best;
    }
    __syncthreads();
    float med = (ni > 0) ? medsh : 0.0f;
    med = clampf(med, -20.0f, 20.0f);

    float denom = (n > 1.0f) ? n : 1.0f;
    float rv[8];
    float ssum = 0.0f;
    #pragma unroll
    for (int i = 0; i < 8; ++i) { rv[i] = (ld[i] - med) * mk[i]; ssum += rv[i]; }
    float rsum = block_reduce_sum(ssum, red, tid);
    float rm = clampf(rsum / denom, -40.0f, 40.0f);

    float vsum_l = 0.0f;
    #pragma unroll
    for (int i = 0; i < 8; ++i) { float dd = rv[i] - rm; vsum_l += dd * dd * mk[i]; }
    float vsum = block_reduce_sum(vsum_l, red, tid);
    float var = clampf(vsum / denom, 1e-4f, 1e4f);

    float inv_sup = 1.0f / denom;
    #pragma unroll
    for (int i = 0; i < 8; ++i) {
        int t = tid + i * 256;
        size_t o = (size_t)b * T_ + t;
        out[OFF5 + o] = mk[i];
        out[OFF6 + o] = ld[i];
        out[OFF7 + o] = rv[i];
        out[OFF8 + o] = mk[i] * inv_sup;
        out[OFF9 + o] = rm * mk[i];
        rr_ws[o] = rv[i];
    }
    if (tid == 0) {
        out[OFF0 + b] = med;
        out[OFF2 + b] = rm;
        out[OFF3 + b] = var;
        float cov = n * (1.0f / (float)T_);
        out[OFF4 + b] = (cov > 0.05f) ? cov : 0.05f;
        sup_ws[b] = n;
    }
}

// ---------------------------------------------------------------------------
// Kernel 2: conv1 gather-GEMM, fp8 MFMA. BM=64 x 512 (two 256-col halves,
//   acc[4][4]). Strided fragment loads (4 x 8 B/step, depth-1 prefetch).
//   launch_bounds MUST stay (256,3): (256,4) forces a 64-VGPR allocation
//   on this compiler (measured twice: R8, R12) -> accumulator spill ->
//   100+ MB scratch WRITE_SIZE, 2x slower. (256,3) = 76 VGPR, no scratch.
// ---------------------------------------------------------------------------
#define H0S 520
__global__ __launch_bounds__(256, 3) void conv1g_kernel(
    const int* __restrict__ ids, const float* __restrict__ rr,
    const float* __restrict__ emb,
    const float* __restrict__ aux_w, const float* __restrict__ aux_b,
    const unsigned char* __restrict__ W1p, const float* __restrict__ bias1,
    unsigned char* __restrict__ H1buf)
{
    __shared__ __align__(16) unsigned char H0s[66 * H0S];   // 34320 B
    __shared__ int   lid[66];
    __shared__ float lrr[66];

    int tile = blockIdx.x;          // 0..31
    int b    = blockIdx.y;          // 0..31
    int r0   = tile << 6;
    int tid  = threadIdx.x;
    int wave = tid >> 6, lane = tid & 63;
    int q = lane >> 4, m16 = lane & 15;

    if (tid < 66) {
        int t = r0 - 2 + tid;
        bool v = (t >= 0);
        lid[tid] = v ? ids[b * T_ + t] : -1;
        lrr[tid] = v ? rr[(size_t)b * T_ + t] : 0.0f;
    }
    __syncthreads();

    {   // gather hidden0 -> fp8 LDS
        int c4 = tid & 127;
        float4 aw = *(const float4*)(aux_w + c4 * 4);
        float4 ab = *(const float4*)(aux_b + c4 * 4);
        int rbase = tid >> 7;
        for (int j = 0; j < 33; ++j) {
            int row = rbase + j * 2;
            int id = lid[row];
            int word = 0;
            if (id >= 0) {
                float vr = lrr[row];
                float4 e = *(const float4*)(emb + (size_t)id * D_ + c4 * 4);
                word = pk4fp8((e.x + vr * aw.x + ab.x) * SCALE_H0,
                              (e.y + vr * aw.y + ab.y) * SCALE_H0,
                              (e.z + vr * aw.z + ab.z) * SCALE_H0,
                              (e.w + vr * aw.w + ab.w) * SCALE_H0);
            }
            *(int*)(&H0s[row * H0S + c4 * 4]) = word;
        }
    }
    __syncthreads();

    unsigned char* Ob = H1buf + ((size_t)b * 2050 + 2 + r0) * 512;

    #pragma unroll
    for (int nh = 0; nh < 2; ++nh) {
        floatx4 acc[4][4];
        #pragma unroll
        for (int i = 0; i < 4; ++i)
            #pragma unroll
            for (int j = 0; j < 4; ++j)
                acc[i][j] = (floatx4){0.f, 0.f, 0.f, 0.f};

        const long* wp[4];
        #pragma unroll
        for (int nt = 0; nt < 4; ++nt) {
            int ntg = nh * 16 + wave * 4 + nt;
            wp[nt] = (const long*)W1p + ((size_t)ntg * 64 + lane);
        }
        long bfr[2][4];
        #pragma unroll
        for (int nt = 0; nt < 4; ++nt) bfr[0][nt] = wp[nt][0];

        for (int s = 0; s < 48; ++s) {
            int cur = s & 1;
            if (s + 1 < 48) {
                #pragma unroll
                for (int nt = 0; nt < 4; ++nt)
                    bfr[cur ^ 1][nt] = wp[nt][(size_t)(s + 1) * 2048]; // 32*64 longs
            }
            int k1 = s >> 4, ci = s & 15;
            #pragma unroll
            for (int mt = 0; mt < 4; ++mt) {
                long afr = *(const long*)(&H0s[(mt * 16 + m16 + k1) * H0S + ci * 32 + q * 8]);
                #pragma unroll
                for (int nt = 0; nt < 4; ++nt)
                    acc[mt][nt] = __builtin_amdgcn_mfma_f32_16x16x32_fp8_fp8(
                        afr, bfr[cur][nt], acc[mt][nt], 0, 0, 0);
            }
        }

        #pragma unroll
        for (int mt = 0; mt < 4; ++mt) {
            #pragma unroll
            for (int nt = 0; nt < 4; ++nt) {
                int col = nh * 256 + wave * 64 + nt * 16 + m16;
                float bsv = bias1[col];
                #pragma unroll
                for (int r = 0; r < 4; ++r) {
                    int row = mt * 16 + q * 4 + r;
                    float v = gelu_exact(acc[mt][nt][r] * INV1 + bsv) * SCALE_A;
                    Ob[(size_t)row * 512 + col] = f2fp8(v);
                }
            }
        }
    }
}

// ---------------------------------------------------------------------------
// Kernel 3 (R13 verbatim): conv2 (fp8 MFMA) + gelu + LN + masked column sums.
//   BM=32 x full 512 cols (acc[2][8] = 64 regs), LN from live accumulators.
//   K-loop: plain load-then-use (NO manual prefetch). Manual double-buffering
//   is falsified on this compiler in BOTH failure modes: register-pressure
//   spill (R8/R9/R10) and v_cndmask select-serialization of the runtime-
//   indexed buffer (R14: 151 -> 322 us, MfmaUtil 29 -> 13, no spill).
//   The compiler's own scheduler does better — leave this loop alone.
// ---------------------------------------------------------------------------
#define H1S 520
__global__ __launch_bounds__(256, 2) void conv2ln_kernel(
    const unsigned char* __restrict__ H1buf, const unsigned char* __restrict__ W2p,
    const float* __restrict__ bias2,
    const float* __restrict__ ln_g, const float* __restrict__ ln_b,
    const float* __restrict__ maskp,
    float* __restrict__ psum, float* __restrict__ psumsq)
{
    __shared__ __align__(16) unsigned char H1s[34 * H1S];   // 17680 B
    __shared__ float mrow[32];
    __shared__ float part[32][4][2];
    __shared__ float tot[32][2];
    __shared__ float colsum[512][2];

    int tile = blockIdx.x;          // 0..63
    int b    = blockIdx.y;          // 0..31
    int r0   = tile << 5;           // output rows r0..r0+31
    int tid  = threadIdx.x;
    int wave = tid >> 6, lane = tid & 63;
    int q = lane >> 4, m16 = lane & 15;
    int nbase = wave << 7;

    const unsigned char* src = H1buf + ((size_t)b * 2050 + r0) * 512;
    for (int g = tid; g < 34 * 32; g += 256) {
        int row = g >> 5, h = g & 31;
        *(float4*)(&H1s[row * H1S + h * 16]) = *(const float4*)(src + (size_t)row * 512 + h * 16);
    }
    if (tid < 32)
        mrow[tid] = clampf(maskp[(size_t)b * T_ + r0 + tid], 0.0f, 1.0f);
    __syncthreads();

    floatx4 acc[2][8];
    #pragma unroll
    for (int i = 0; i < 2; ++i)
        #pragma unroll
        for (int j = 0; j < 8; ++j)
            acc[i][j] = (floatx4){0.f, 0.f, 0.f, 0.f};

    for (int s = 0; s < 48; ++s) {
        int k2 = s >> 4, ci = s & 15;
        long f[8];
        #pragma unroll
        for (int nt = 0; nt < 8; ++nt) {
            int ntg = wave * 8 + nt;
            f[nt] = *((const long*)W2p + ((size_t)(s * 32 + ntg) * 64 + lane));
        }
        #pragma unroll
        for (int mt = 0; mt < 2; ++mt) {
            long afr = *(const long*)(&H1s[(mt * 16 + m16 + k2) * H1S + ci * 32 + q * 8]);
            #pragma unroll
            for (int nt = 0; nt < 8; ++nt)
                acc[mt][nt] = __builtin_amdgcn_mfma_f32_16x16x32_fp8_fp8(
                    afr, f[nt], acc[mt][nt], 0, 0, 0);
        }
    }

    // epilogue: descale + bias + gelu
    #pragma unroll
    for (int mt = 0; mt < 2; ++mt)
        #pragma unroll
        for (int nt = 0; nt < 8; ++nt) {
            int col = nbase + nt * 16 + m16;
            float bsv = bias2[col];
            #pragma unroll
            for (int r = 0; r < 4; ++r)
                acc[mt][nt][r] = gelu_exact(acc[mt][nt][r] * INV2 + bsv);
        }

    // LN row stats
    #pragma unroll
    for (int mt = 0; mt < 2; ++mt) {
        #pragma unroll
        for (int r = 0; r < 4; ++r) {
            float rs = 0.f, rq = 0.f;
            #pragma unroll
            for (int nt = 0; nt < 8; ++nt) {
                float v = acc[mt][nt][r];
                rs += v; rq += v * v;
            }
            rs += __shfl_xor(rs, 1);  rq += __shfl_xor(rq, 1);
            rs += __shfl_xor(rs, 2);  rq += __shfl_xor(rq, 2);
            rs += __shfl_xor(rs, 4);  rq += __shfl_xor(rq, 4);
            rs += __shfl_xor(rs, 8);  rq += __shfl_xor(rq, 8);
            if (m16 == 0) {
                int row = mt * 16 + q * 4 + r;
                part[row][wave][0] = rs;
                part[row][wave][1] = rq;
            }
        }
    }
    __syncthreads();
    if (tid < 64) {
        int row = tid >> 1, j = tid & 1;
        tot[row][j] = part[row][0][j] + part[row][1][j] + part[row][2][j] + part[row][3][j];
    }
    __syncthreads();

    float meanv[2][4], rstdv[2][4];
    #pragma unroll
    for (int mt = 0; mt < 2; ++mt)
        #pragma unroll
        for (int r = 0; r < 4; ++r) {
            int row = mt * 16 + q * 4 + r;
            float m = tot[row][0] * (1.0f / D_);
            float var = tot[row][1] * (1.0f / D_) - m * m;
            meanv[mt][r] = m;
            rstdv[mt][r] = rsqrtf((var > 0.0f ? var : 0.0f) + 1e-5f);
        }

    float cs[8], cq[8];
    #pragma unroll
    for (int nt = 0; nt < 8; ++nt) { cs[nt] = 0.f; cq[nt] = 0.f; }
    #pragma unroll
    for (int mt = 0; mt < 2; ++mt) {
        #pragma unroll
        for (int r = 0; r < 4; ++r) {
            int row = mt * 16 + q * 4 + r;
            float mk = mrow[row];
            float m = meanv[mt][r], rs = rstdv[mt][r];
            #pragma unroll
            for (int nt = 0; nt < 8; ++nt) {
                int col = nbase + nt * 16 + m16;
                float xn = ((acc[mt][nt][r] - m) * rs * ln_g[col] + ln_b[col]) * mk;
                cs[nt] += xn;
                cq[nt] += xn * xn;
            }
        }
    }
    #pragma unroll
    for (int nt = 0; nt < 8; ++nt) {
        cs[nt] += __shfl_xor(cs[nt], 16);  cq[nt] += __shfl_xor(cq[nt], 16);
        cs[nt] += __shfl_xor(cs[nt], 32);  cq[nt] += __shfl_xor(cq[nt], 32);
    }
    if (lane < 16) {
        #pragma unroll
        for (int nt = 0; nt < 8; ++nt) {
            int col = nbase + nt * 16 + m16;
            colsum[col][0] = cs[nt];
            colsum[col][1] = cq[nt];
        }
    }
    __syncthreads();
    for (int i = tid; i < 512; i += 256) {
        atomicAdd(&psum[(size_t)b * D_ + i], colsum[i][0]);
        atomicAdd(&psumsq[(size_t)b * D_ + i], colsum[i][1]);
    }
}

// ---------------------------------------------------------------------------
// Kernel 4: per-batch MLP head: mean/std -> p1/gelu -> p2/tanh, coeff_norm
// ---------------------------------------------------------------------------
__global__ __launch_bounds__(512) void mlp_kernel(
    const float* __restrict__ psum, const float* __restrict__ psumsq,
    const float* __restrict__ sup_ws,
    const float* __restrict__ p1w, const float* __restrict__ p1b,
    const float* __restrict__ p2w, const float* __restrict__ p2b,
    float* __restrict__ out)
{
    int b = blockIdx.x;
    int d = threadIdx.x;
    __shared__ float h[2 * D_];
    __shared__ float s1[D_];
    __shared__ float red[512];

    float n = sup_ws[b];
    float denom = (n > 1.0f) ? n : 1.0f;
    float S = psum[(size_t)b * D_ + d];
    float Q = psumsq[(size_t)b * D_ + d];
    float mean = S / denom;
    float msum = Q - 2.0f * mean * S + n * mean * mean;
    float arg = msum / denom + 1e-6f;
    float sd = sqrtf((arg > 0.0f) ? arg : 0.0f);
    h[d] = mean;
    h[D_ + d] = sd;
    __syncthreads();

    float z = p1b[d];
    const float4* w4 = (const float4*)(p1w + (size_t)d * (2 * D_));
    for (int jj = 0; jj < 2 * D_ / 4; ++jj) {
        float4 wv = w4[jj];
        z += h[jj * 4 + 0] * wv.x + h[jj * 4 + 1] * wv.y
           + h[jj * 4 + 2] * wv.z + h[jj * 4 + 3] * wv.w;
    }
    s1[d] = gelu_exact(z);
    __syncthreads();

    float z2 = p2b[d];
    const float4* w24 = (const float4*)(p2w + (size_t)d * D_);
    for (int jj = 0; jj < D_ / 4; ++jj) {
        float4 wv = w24[jj];
        z2 += s1[jj * 4 + 0] * wv.x + s1[jj * 4 + 1] * wv.y
            + s1[jj * 4 + 2] * wv.z + s1[jj * 4 + 3] * wv.w;
    }
    float st = tanhf(z2);
    if (!(n > 0.0f)) st = 0.0f;
    out[OFF1 + (size_t)b * D_ + d] = st;

    red[d] = st * st;
    __syncthreads();
    for (int s = 256; s > 0; s >>= 1) {
        if (d < s) red[d] += red[d + s];
        __syncthreads();
    }
    if (d == 0) out[OFF10 + b] = sqrtf(red[0]);
}

// ---------------------------------------------------------------------------
extern "C" void kernel_launch(void* const* d_in, const int* in_sizes, int n_in,
                              void* d_out, int out_size, void* d_ws, size_t ws_size,
                              hipStream_t stream) {
    (void)in_sizes; (void)n_in; (void)out_size; (void)ws_size;
    const int*   unit_ids = (const int*)d_in[0];
    const float* dur      = (const float*)d_in[1];
    const float* mask     = (const float*)d_in[2];
    const float* emb      = (const float*)d_in[3];
    const float* aux_w    = (const float*)d_in[4];
    const float* aux_b    = (const float*)d_in[5];
    const float* conv1_w  = (const float*)d_in[6];
    const float* conv1_b  = (const float*)d_in[7];
    const float* conv2_w  = (const float*)d_in[8];
    const float* conv2_b  = (const float*)d_in[9];
    const float* ln_g     = (const float*)d_in[10];
    const float* ln_b     = (const float*)d_in[11];
    const float* p1_w     = (const float*)d_in[12];
    const float* p1_b     = (const float*)d_in[13];
    const float* p2_w     = (const float*)d_in[14];
    const float* p2_b     = (const float*)d_in[15];
    float* out = (float*)d_out;

    char* ws = (char*)d_ws;
    float*          rr     = (float*)(ws + WS_RR);
    float*          sup    = (float*)(ws + WS_SUP);
    float*          psum   = (float*)(ws + WS_PSUM);
    float*          psumsq = (float*)(ws + WS_PSUMSQ);
    unsigned char*  W1p    = (unsigned char*)(ws + WS_W1P);
    unsigned char*  W2p    = (unsigned char*)(ws + WS_W2P);
    unsigned char*  H1buf  = (unsigned char*)(ws + WS_H1);

    init_kernel<<<dim3(64), dim3(256), 0, stream>>>(
        dur, mask, conv1_w, conv2_w, W1p, W2p, H1buf, rr, sup, psum, out);
    conv1g_kernel<<<dim3(32, 32), dim3(256), 0, stream>>>(
        unit_ids, rr, emb, aux_w, aux_b, W1p, conv1_b, H1buf);
    conv2ln_kernel<<<dim3(64, 32), dim3(256), 0, stream>>>(
        H1buf, W2p, conv2_b, ln_g, ln_b, mask, psum, psumsq);
    mlp_kernel<<<dim3(B_), dim3(512), 0, stream>>>(
        psum, psumsq, sup, p1_w, p1_b, p2_w, p2_b, out);
}

// Round 16
// 383.526 us; speedup vs baseline: 1.5980x; 1.1349x over previous
//
#include <hip/hip_runtime.h>
#include <hip/hip_bf16.h>
#include <math.h>

#define B_  32
#define T_  2048
#define D_  512
#define V_  1024
#define K_  3

typedef __attribute__((ext_vector_type(8))) short   short8;
typedef __attribute__((ext_vector_type(4))) float   floatx4;

#define SCALE_H0 256.0f        // hidden0 fp8 scale (conv1 input)
#define SCALE_A  64.0f         // H1 activation fp8 scale (conv2 input)
#define SCALE_W  16.0f         // weight fp8 scale (both convs)
#define INV1 (1.0f/(SCALE_H0*SCALE_W))
#define INV2 (1.0f/(SCALE_A*SCALE_W))

// ---- output flat offsets (elements, fp32) ----
#define OFF0 0        // global_rate      [32]
#define OFF1 32       // summary_state    [32*512]
#define OFF2 16416    // residual_mean    [32]
#define OFF3 16448    // residual_var     [32]
#define OFF4 16480    // coverage         [32]
#define OFF5 16512    // mask             [32*2048]
#define OFF6 82048    // logdur           [32*2048]
#define OFF7 147584   // ref_residual     [32*2048]
#define OFF8 213120   // attn             [32*2048]
#define OFF9 278656   // prompt_role_fit  [32*2048]
#define OFF10 344192  // coeff_norm       [32]

// ---- workspace byte offsets (end 35,619,072 B < proven 36.34 MB) ----
#define WS_RR     0          // fp32 [32][2048]              262144 B
#define WS_SUP    262144     // fp32 [32]                       128 B
#define WS_PSUM   262272     // fp32 [32][512]                65536 B
#define WS_PSUMSQ 327808     // fp32 [32][512]                65536 B
#define WS_W1P    393344     // fp8  frag-packed conv1 w     786432 B
#define WS_W2P    1179776    // fp8  frag-packed conv2 w     786432 B
#define WS_H1     1966208    // fp8  [32][2050][512]       33587200 B
#define WS_S1     35553408   // fp32 [32][512] mlp hidden     65536 B
#define WS_NRM    35618944   // fp32 [32] coeff_norm accum      128 B

__device__ __forceinline__ float clampf(float v, float lo, float hi) {
    v = (v > lo) ? v : lo;
    return (v < hi) ? v : hi;
}
// NOTE: keep gelu_exact (erff) in the conv epilogues. The inlined tanh-form
// gelu_fast triggered accumulator spill-to-scratch in R8/R9/R10 (FETCH/WRITE
// blew up 10x, conv1g 130 -> 366 us). erff's call structure keeps acc
// register-resident. Do not "optimize" this again without checking WRITE_SIZE.
__device__ __forceinline__ float gelu_exact(float v) {
    return 0.5f * v * (1.0f + erff(v * 0.70710678118654752440f));
}
__device__ __forceinline__ unsigned char f2fp8(float x) {
    int v = __builtin_amdgcn_cvt_pk_fp8_f32(x, x, 0, false);
    return (unsigned char)(v & 0xFF);
}
__device__ __forceinline__ int pk4fp8(float a, float b, float c, float d) {
    int p0 = __builtin_amdgcn_cvt_pk_fp8_f32(a, b, 0, false);
    int p1 = __builtin_amdgcn_cvt_pk_fp8_f32(c, d, 0, false);
    return (p1 << 16) | (p0 & 0xFFFF);
}

__device__ __forceinline__ float block_reduce_sum(float v, float* red, int tid) {
    __syncthreads();
    red[tid] = v;
    __syncthreads();
    for (int s = 128; s > 0; s >>= 1) {
        if (tid < s) red[tid] += red[tid + s];
        __syncthreads();
    }
    float r = red[0];
    __syncthreads();
    return r;
}

// ---------------------------------------------------------------------------
// Kernel 1: MERGED init — blocks 0..31: per-batch stats (histogram-select
//   exact median + T-wise outputs); blocks 32..63: LDS-transpose weight
//   prepack + psum/H1-pad zeroing.
// ---------------------------------------------------------------------------
#define NB 2048
#define HLO (-9.3f)
#define HSC ((float)NB / 10.05f)     // range [-9.3, 0.75]
#define WLS 1544                     // LDS row stride (1536 + 8 pad)
__global__ __launch_bounds__(256) void init_kernel(
    const float* __restrict__ dur, const float* __restrict__ maskp,
    const float* __restrict__ w1, const float* __restrict__ w2,
    unsigned char* __restrict__ W1p, unsigned char* __restrict__ W2p,
    unsigned char* __restrict__ H1buf,
    float* __restrict__ rr_ws, float* __restrict__ sup_ws,
    float* __restrict__ psum, float* __restrict__ out)
{
    int tid = threadIdx.x;

    if (blockIdx.x >= 32) {
        // ---------------- prepack part (LDS transpose) ----------------
        __shared__ unsigned char Wl[2 * 16 * WLS];   // 49408 B
        int ntg = blockIdx.x - 32;                   // 0..31 (16-col group)
        int lane = tid & 63, wave = tid >> 6;

        #pragma unroll
        for (int ws = 0; ws < 2; ++ws) {
            const float* wsrc = (ws ? w2 : w1) + (size_t)ntg * 16 * 1536;
            for (int i = tid; i < 6144; i += 256) {      // 16 cols x 1536 f
                float4 v = ((const float4*)wsrc)[i];
                int col_local = i / 384;                 // 384 float4 per col
                int pos = (i % 384) * 4;
                int word = pk4fp8(v.x * SCALE_W, v.y * SCALE_W,
                                  v.z * SCALE_W, v.w * SCALE_W);
                *(int*)(&Wl[(ws * 16 + col_local) * WLS + pos]) = word;
            }
        }
        __syncthreads();

        int cl = lane & 15, qq = lane >> 4;
        #pragma unroll
        for (int ws = 0; ws < 2; ++ws) {
            unsigned char* dst = ws ? W2p : W1p;
            for (int s = wave; s < 48; s += 4) {
                int ci = s & 15, k = s >> 4;
                const unsigned char* row = &Wl[(ws * 16 + cl) * WLS];
                int kin = ci * 32 + qq * 8;
                unsigned char bb[8];
                #pragma unroll
                for (int e = 0; e < 8; ++e)
                    bb[e] = row[(kin + e) * 3 + k];
                *(double*)(dst + ((size_t)(s * 32 + ntg) * 64 + lane) * 8) =
                    *(double*)bb;
            }
        }

        // zeroing: 32 blocks x 256 threads x 4 = 32768 elems each array
        int pid2 = ntg * 256 + tid;
        #pragma unroll
        for (int j = 0; j < 4; ++j) {
            int idx = pid2 + j * 8192;
            psum[idx] = 0.0f;                      // psum + psumsq contiguous
            int b = idx >> 10;
            int r = (idx >> 9) & 1;
            int d = idx & 511;
            H1buf[((size_t)b * 2050 + r) * 512 + d] = 0;
        }
        return;
    }

    // ---------------- stats part ----------------
    __shared__ int   hist[NB];
    __shared__ int   csum[256];
    __shared__ float red[256];
    __shared__ float cand[128];
    __shared__ float nsh, medsh;
    __shared__ int   sh_tb, sh_cb, sh_candn;

    int b = blockIdx.x;
    const float* durb = dur + (size_t)b * T_;
    const float* mkb  = maskp + (size_t)b * T_;

    float ld[8], mk[8];
    int   bn[8];
    float cnt = 0.0f;
    #pragma unroll
    for (int i = 0; i < 8; ++i) hist[tid * 8 + i] = 0;
    __syncthreads();
    #pragma unroll
    for (int i = 0; i < 8; ++i) {
        int t = tid + i * 256;
        float m = clampf(mkb[t], 0.0f, 1.0f);
        float dv = durb[t];
        dv = (dv >= 1e-4f) ? dv : 1e-4f;
        float l = logf(dv) * m;
        ld[i] = l; mk[i] = m;
        int bin = (int)((l - HLO) * HSC);
        bin = (bin < 0) ? 0 : ((bin > NB - 1) ? NB - 1 : bin);
        bn[i] = bin;
        if (m > 0.5f) { cnt += 1.0f; atomicAdd(&hist[bin], 1); }
    }
    float n = block_reduce_sum(cnt, red, tid);   // barriers make hist visible
    if (tid == 0) { nsh = n; sh_candn = 0; medsh = 0.0f; }

    // chunk sums + inclusive scan (Hillis-Steele)
    {
        int cs = 0;
        #pragma unroll
        for (int i = 0; i < 8; ++i) cs += hist[tid * 8 + i];
        csum[tid] = cs;
        __syncthreads();
        for (int off = 1; off < 256; off <<= 1) {
            int v = (tid >= off) ? csum[tid - off] : 0;
            __syncthreads();
            csum[tid] += v;
            __syncthreads();
        }
    }
    int ni = (int)(n + 0.5f);
    int k  = (ni > 0) ? ((ni - 1) >> 1) : 0;     // 0-indexed lower-median rank
    {
        int prevIncl = (tid > 0) ? csum[tid - 1] : 0;
        if (ni > 0 && k >= prevIncl && k < csum[tid]) {   // unique owner thread
            int cum = prevIncl, tb = tid * 8;
            #pragma unroll
            for (int i = 0; i < 8; ++i) {
                int c = hist[tid * 8 + i];
                if (k < cum + c) { tb = tid * 8 + i; break; }
                cum += c;
            }
            sh_tb = tb; sh_cb = cum;
        }
    }
    __syncthreads();
    // collect candidates in target bin
    if (ni > 0) {
        int tb = sh_tb;
        #pragma unroll
        for (int i = 0; i < 8; ++i) {
            if (mk[i] > 0.5f && bn[i] == tb) {
                int p = atomicAdd(&sh_candn, 1);
                if (p < 128) cand[p] = ld[i];
            }
        }
    }
    __syncthreads();
    if (tid == 0 && ni > 0) {
        int m = k - sh_cb;
        int cn = (sh_candn < 128) ? sh_candn : 128;
        float best = cand[0];
        for (int i = 0; i < cn; ++i) {
            int rank = 0;
            for (int j = 0; j < cn; ++j)
                rank += (cand[j] < cand[i]) || (cand[j] == cand[i] && j < i);
            if (rank == m) { best = cand[i]; break; }
        }
        medsh = best;
    }
    __syncthreads();
    float med = (ni > 0) ? medsh : 0.0f;
    med = clampf(med, -20.0f, 20.0f);

    float denom = (n > 1.0f) ? n : 1.0f;
    float rv[8];
    float ssum = 0.0f;
    #pragma unroll
    for (int i = 0; i < 8; ++i) { rv[i] = (ld[i] - med) * mk[i]; ssum += rv[i]; }
    float rsum = block_reduce_sum(ssum, red, tid);
    float rm = clampf(rsum / denom, -40.0f, 40.0f);

    float vsum_l = 0.0f;
    #pragma unroll
    for (int i = 0; i < 8; ++i) { float dd = rv[i] - rm; vsum_l += dd * dd * mk[i]; }
    float vsum = block_reduce_sum(vsum_l, red, tid);
    float var = clampf(vsum / denom, 1e-4f, 1e4f);

    float inv_sup = 1.0f / denom;
    #pragma unroll
    for (int i = 0; i < 8; ++i) {
        int t = tid + i * 256;
        size_t o = (size_t)b * T_ + t;
        out[OFF5 + o] = mk[i];
        out[OFF6 + o] = ld[i];
        out[OFF7 + o] = rv[i];
        out[OFF8 + o] = mk[i] * inv_sup;
        out[OFF9 + o] = rm * mk[i];
        rr_ws[o] = rv[i];
    }
    if (tid == 0) {
        out[OFF0 + b] = med;
        out[OFF2 + b] = rm;
        out[OFF3 + b] = var;
        float cov = n * (1.0f / (float)T_);
        out[OFF4 + b] = (cov > 0.05f) ? cov : 0.05f;
        sup_ws[b] = n;
    }
}

// ---------------------------------------------------------------------------
// Kernel 2: conv1 gather-GEMM, fp8 MFMA. BM=64 x 512 (two 256-col halves,
//   acc[4][4]). Strided fragment loads (4 x 8 B/step, depth-1 prefetch).
//   launch_bounds MUST stay (256,3): (256,4) forces a 64-VGPR allocation
//   on this compiler (measured twice: R8, R12) -> accumulator spill ->
//   100+ MB scratch WRITE_SIZE, 2x slower. (256,3) = 76 VGPR, no scratch.
// ---------------------------------------------------------------------------
#define H0S 520
__global__ __launch_bounds__(256, 3) void conv1g_kernel(
    const int* __restrict__ ids, const float* __restrict__ rr,
    const float* __restrict__ emb,
    const float* __restrict__ aux_w, const float* __restrict__ aux_b,
    const unsigned char* __restrict__ W1p, const float* __restrict__ bias1,
    unsigned char* __restrict__ H1buf)
{
    __shared__ __align__(16) unsigned char H0s[66 * H0S];   // 34320 B
    __shared__ int   lid[66];
    __shared__ float lrr[66];

    int tile = blockIdx.x;          // 0..31
    int b    = blockIdx.y;          // 0..31
    int r0   = tile << 6;
    int tid  = threadIdx.x;
    int wave = tid >> 6, lane = tid & 63;
    int q = lane >> 4, m16 = lane & 15;

    if (tid < 66) {
        int t = r0 - 2 + tid;
        bool v = (t >= 0);
        lid[tid] = v ? ids[b * T_ + t] : -1;
        lrr[tid] = v ? rr[(size_t)b * T_ + t] : 0.0f;
    }
    __syncthreads();

    {   // gather hidden0 -> fp8 LDS
        int c4 = tid & 127;
        float4 aw = *(const float4*)(aux_w + c4 * 4);
        float4 ab = *(const float4*)(aux_b + c4 * 4);
        int rbase = tid >> 7;
        for (int j = 0; j < 33; ++j) {
            int row = rbase + j * 2;
            int id = lid[row];
            int word = 0;
            if (id >= 0) {
                float vr = lrr[row];
                float4 e = *(const float4*)(emb + (size_t)id * D_ + c4 * 4);
                word = pk4fp8((e.x + vr * aw.x + ab.x) * SCALE_H0,
                              (e.y + vr * aw.y + ab.y) * SCALE_H0,
                              (e.z + vr * aw.z + ab.z) * SCALE_H0,
                              (e.w + vr * aw.w + ab.w) * SCALE_H0);
            }
            *(int*)(&H0s[row * H0S + c4 * 4]) = word;
        }
    }
    __syncthreads();

    unsigned char* Ob = H1buf + ((size_t)b * 2050 + 2 + r0) * 512;

    #pragma unroll
    for (int nh = 0; nh < 2; ++nh) {
        floatx4 acc[4][4];
        #pragma unroll
        for (int i = 0; i < 4; ++i)
            #pragma unroll
            for (int j = 0; j < 4; ++j)
                acc[i][j] = (floatx4){0.f, 0.f, 0.f, 0.f};

        const long* wp[4];
        #pragma unroll
        for (int nt = 0; nt < 4; ++nt) {
            int ntg = nh * 16 + wave * 4 + nt;
            wp[nt] = (const long*)W1p + ((size_t)ntg * 64 + lane);
        }
        long bfr[2][4];
        #pragma unroll
        for (int nt = 0; nt < 4; ++nt) bfr[0][nt] = wp[nt][0];

        for (int s = 0; s < 48; ++s) {
            int cur = s & 1;
            if (s + 1 < 48) {
                #pragma unroll
                for (int nt = 0; nt < 4; ++nt)
                    bfr[cur ^ 1][nt] = wp[nt][(size_t)(s + 1) * 2048]; // 32*64 longs
            }
            int k1 = s >> 4, ci = s & 15;
            #pragma unroll
            for (int mt = 0; mt < 4; ++mt) {
                long afr = *(const long*)(&H0s[(mt * 16 + m16 + k1) * H0S + ci * 32 + q * 8]);
                #pragma unroll
                for (int nt = 0; nt < 4; ++nt)
                    acc[mt][nt] = __builtin_amdgcn_mfma_f32_16x16x32_fp8_fp8(
                        afr, bfr[cur][nt], acc[mt][nt], 0, 0, 0);
            }
        }

        #pragma unroll
        for (int mt = 0; mt < 4; ++mt) {
            #pragma unroll
            for (int nt = 0; nt < 4; ++nt) {
                int col = nh * 256 + wave * 64 + nt * 16 + m16;
                float bsv = bias1[col];
                #pragma unroll
                for (int r = 0; r < 4; ++r) {
                    int row = mt * 16 + q * 4 + r;
                    float v = gelu_exact(acc[mt][nt][r] * INV1 + bsv) * SCALE_A;
                    Ob[(size_t)row * 512 + col] = f2fp8(v);
                }
            }
        }
    }
}

// ---------------------------------------------------------------------------
// Kernel 3: conv2 (fp8 MFMA) + gelu + LN + masked column sums.
//   BM=32 x full 512 cols (acc[2][8] = 64 regs), LN from live accumulators.
//   K-loop: plain load-then-use + "#pragma unroll 2" (compile-time indices
//   only — manual double-buffering is falsified in both its spill mode
//   (R8/R9/R10) and its cndmask-select mode (R14: 151 -> 322 us)).
//   TRIPWIRE: WRITE_SIZE >> 8 MB or dur > 151 us => the unroll hurt => drop it.
// ---------------------------------------------------------------------------
#define H1S 520
__global__ __launch_bounds__(256, 2) void conv2ln_kernel(
    const unsigned char* __restrict__ H1buf, const unsigned char* __restrict__ W2p,
    const float* __restrict__ bias2,
    const float* __restrict__ ln_g, const float* __restrict__ ln_b,
    const float* __restrict__ maskp,
    float* __restrict__ psum, float* __restrict__ psumsq)
{
    __shared__ __align__(16) unsigned char H1s[34 * H1S];   // 17680 B
    __shared__ float mrow[32];
    __shared__ float part[32][4][2];
    __shared__ float tot[32][2];
    __shared__ float colsum[512][2];

    int tile = blockIdx.x;          // 0..63
    int b    = blockIdx.y;          // 0..31
    int r0   = tile << 5;           // output rows r0..r0+31
    int tid  = threadIdx.x;
    int wave = tid >> 6, lane = tid & 63;
    int q = lane >> 4, m16 = lane & 15;
    int nbase = wave << 7;

    const unsigned char* src = H1buf + ((size_t)b * 2050 + r0) * 512;
    for (int g = tid; g < 34 * 32; g += 256) {
        int row = g >> 5, h = g & 31;
        *(float4*)(&H1s[row * H1S + h * 16]) = *(const float4*)(src + (size_t)row * 512 + h * 16);
    }
    if (tid < 32)
        mrow[tid] = clampf(maskp[(size_t)b * T_ + r0 + tid], 0.0f, 1.0f);
    __syncthreads();

    floatx4 acc[2][8];
    #pragma unroll
    for (int i = 0; i < 2; ++i)
        #pragma unroll
        for (int j = 0; j < 8; ++j)
            acc[i][j] = (floatx4){0.f, 0.f, 0.f, 0.f};

    #pragma unroll 2
    for (int s = 0; s < 48; ++s) {
        int k2 = s >> 4, ci = s & 15;
        long f[8];
        #pragma unroll
        for (int nt = 0; nt < 8; ++nt) {
            int ntg = wave * 8 + nt;
            f[nt] = *((const long*)W2p + ((size_t)(s * 32 + ntg) * 64 + lane));
        }
        #pragma unroll
        for (int mt = 0; mt < 2; ++mt) {
            long afr = *(const long*)(&H1s[(mt * 16 + m16 + k2) * H1S + ci * 32 + q * 8]);
            #pragma unroll
            for (int nt = 0; nt < 8; ++nt)
                acc[mt][nt] = __builtin_amdgcn_mfma_f32_16x16x32_fp8_fp8(
                    afr, f[nt], acc[mt][nt], 0, 0, 0);
        }
    }

    // epilogue: descale + bias + gelu
    #pragma unroll
    for (int mt = 0; mt < 2; ++mt)
        #pragma unroll
        for (int nt = 0; nt < 8; ++nt) {
            int col = nbase + nt * 16 + m16;
            float bsv = bias2[col];
            #pragma unroll
            for (int r = 0; r < 4; ++r)
                acc[mt][nt][r] = gelu_exact(acc[mt][nt][r] * INV2 + bsv);
        }

    // LN row stats
    #pragma unroll
    for (int mt = 0; mt < 2; ++mt) {
        #pragma unroll
        for (int r = 0; r < 4; ++r) {
            float rs = 0.f, rq = 0.f;
            #pragma unroll
            for (int nt = 0; nt < 8; ++nt) {
                float v = acc[mt][nt][r];
                rs += v; rq += v * v;
            }
            rs += __shfl_xor(rs, 1);  rq += __shfl_xor(rq, 1);
            rs += __shfl_xor(rs, 2);  rq += __shfl_xor(rq, 2);
            rs += __shfl_xor(rs, 4);  rq += __shfl_xor(rq, 4);
            rs += __shfl_xor(rs, 8);  rq += __shfl_xor(rq, 8);
            if (m16 == 0) {
                int row = mt * 16 + q * 4 + r;
                part[row][wave][0] = rs;
                part[row][wave][1] = rq;
            }
        }
    }
    __syncthreads();
    if (tid < 64) {
        int row = tid >> 1, j = tid & 1;
        tot[row][j] = part[row][0][j] + part[row][1][j] + part[row][2][j] + part[row][3][j];
    }
    __syncthreads();

    float meanv[2][4], rstdv[2][4];
    #pragma unroll
    for (int mt = 0; mt < 2; ++mt)
        #pragma unroll
        for (int r = 0; r < 4; ++r) {
            int row = mt * 16 + q * 4 + r;
            float m = tot[row][0] * (1.0f / D_);
            float var = tot[row][1] * (1.0f / D_) - m * m;
            meanv[mt][r] = m;
            rstdv[mt][r] = rsqrtf((var > 0.0f ? var : 0.0f) + 1e-5f);
        }

    float cs[8], cq[8];
    #pragma unroll
    for (int nt = 0; nt < 8; ++nt) { cs[nt] = 0.f; cq[nt] = 0.f; }
    #pragma unroll
    for (int mt = 0; mt < 2; ++mt) {
        #pragma unroll
        for (int r = 0; r < 4; ++r) {
            int row = mt * 16 + q * 4 + r;
            float mk = mrow[row];
            float m = meanv[mt][r], rs = rstdv[mt][r];
            #pragma unroll
            for (int nt = 0; nt < 8; ++nt) {
                int col = nbase + nt * 16 + m16;
                float xn = ((acc[mt][nt][r] - m) * rs * ln_g[col] + ln_b[col]) * mk;
                cs[nt] += xn;
                cq[nt] += xn * xn;
            }
        }
    }
    #pragma unroll
    for (int nt = 0; nt < 8; ++nt) {
        cs[nt] += __shfl_xor(cs[nt], 16);  cq[nt] += __shfl_xor(cq[nt], 16);
        cs[nt] += __shfl_xor(cs[nt], 32);  cq[nt] += __shfl_xor(cq[nt], 32);
    }
    if (lane < 16) {
        #pragma unroll
        for (int nt = 0; nt < 8; ++nt) {
            int col = nbase + nt * 16 + m16;
            colsum[col][0] = cs[nt];
            colsum[col][1] = cq[nt];
        }
    }
    __syncthreads();
    for (int i = tid; i < 512; i += 256) {
        atomicAdd(&psum[(size_t)b * D_ + i], colsum[i][0]);
        atomicAdd(&psumsq[(size_t)b * D_ + i], colsum[i][1]);
    }
}

// ---------------------------------------------------------------------------
// Kernels 4a/4b/4c: MLP head split for parallelism (was one 32-block kernel
//   reading all 3 MB of p1w/p2w per block — 1/8 machine utilization).
//   mlp1: grid (32,4) — h vector + p1 GEMM slice -> gelu -> s1_ws
//   mlp2: grid (32,4) — p2 GEMM slice -> tanh -> out + st^2 partials
//   mlp3: 1 block    — sqrt of accumulated norms
// ---------------------------------------------------------------------------
__global__ __launch_bounds__(128) void mlp1_kernel(
    const float* __restrict__ psum, const float* __restrict__ psumsq,
    const float* __restrict__ sup_ws,
    const float* __restrict__ p1w, const float* __restrict__ p1b,
    float* __restrict__ s1_ws, float* __restrict__ nrm_ws)
{
    int b = blockIdx.x, jt = blockIdx.y;
    int tid = threadIdx.x;
    __shared__ float h[2 * D_];

    float n = sup_ws[b];
    float denom = (n > 1.0f) ? n : 1.0f;
    for (int i = tid; i < D_; i += 128) {
        float S = psum[(size_t)b * D_ + i];
        float Q = psumsq[(size_t)b * D_ + i];
        float mean = S / denom;
        float msum = Q - 2.0f * mean * S + n * mean * mean;
        float arg = msum / denom + 1e-6f;
        h[i] = mean;
        h[D_ + i] = sqrtf((arg > 0.0f) ? arg : 0.0f);
    }
    if (jt == 0 && tid == 0) nrm_ws[b] = 0.0f;
    __syncthreads();

    int d = jt * 128 + tid;
    float z = p1b[d];
    const float4* w4 = (const float4*)(p1w + (size_t)d * (2 * D_));
    for (int jj = 0; jj < 2 * D_ / 4; ++jj) {
        float4 wv = w4[jj];
        z += h[jj * 4 + 0] * wv.x + h[jj * 4 + 1] * wv.y
           + h[jj * 4 + 2] * wv.z + h[jj * 4 + 3] * wv.w;
    }
    s1_ws[(size_t)b * D_ + d] = gelu_exact(z);
}

__global__ __launch_bounds__(128) void mlp2_kernel(
    const float* __restrict__ s1_ws, const float* __restrict__ sup_ws,
    const float* __restrict__ p2w, const float* __restrict__ p2b,
    float* __restrict__ nrm_ws, float* __restrict__ out)
{
    int b = blockIdx.x, jt = blockIdx.y;
    int tid = threadIdx.x;
    __shared__ float s1[D_];
    __shared__ float red[128];

    for (int i = tid; i < D_; i += 128) s1[i] = s1_ws[(size_t)b * D_ + i];
    __syncthreads();

    int d = jt * 128 + tid;
    float z2 = p2b[d];
    const float4* w24 = (const float4*)(p2w + (size_t)d * D_);
    for (int jj = 0; jj < D_ / 4; ++jj) {
        float4 wv = w24[jj];
        z2 += s1[jj * 4 + 0] * wv.x + s1[jj * 4 + 1] * wv.y
            + s1[jj * 4 + 2] * wv.z + s1[jj * 4 + 3] * wv.w;
    }
    float n = sup_ws[b];
    float st = tanhf(z2);
    if (!(n > 0.0f)) st = 0.0f;
    out[OFF1 + (size_t)b * D_ + d] = st;

    red[tid] = st * st;
    __syncthreads();
    for (int s = 64; s > 0; s >>= 1) {
        if (tid < s) red[tid] += red[tid + s];
        __syncthreads();
    }
    if (tid == 0) atomicAdd(&nrm_ws[b], red[0]);
}

__global__ __launch_bounds__(64) void mlp3_kernel(
    const float* __restrict__ nrm_ws, float* __restrict__ out)
{
    int b = threadIdx.x;
    if (b < B_) out[OFF10 + b] = sqrtf(nrm_ws[b]);
}

// ---------------------------------------------------------------------------
extern "C" void kernel_launch(void* const* d_in, const int* in_sizes, int n_in,
                              void* d_out, int out_size, void* d_ws, size_t ws_size,
                              hipStream_t stream) {
    (void)in_sizes; (void)n_in; (void)out_size; (void)ws_size;
    const int*   unit_ids = (const int*)d_in[0];
    const float* dur      = (const float*)d_in[1];
    const float* mask     = (const float*)d_in[2];
    const float* emb      = (const float*)d_in[3];
    const float* aux_w    = (const float*)d_in[4];
    const float* aux_b    = (const float*)d_in[5];
    const float* conv1_w  = (const float*)d_in[6];
    const float* conv1_b  = (const float*)d_in[7];
    const float* conv2_w  = (const float*)d_in[8];
    const float* conv2_b  = (const float*)d_in[9];
    const float* ln_g     = (const float*)d_in[10];
    const float* ln_b     = (const float*)d_in[11];
    const float* p1_w     = (const float*)d_in[12];
    const float* p1_b     = (const float*)d_in[13];
    const float* p2_w     = (const float*)d_in[14];
    const float* p2_b     = (const float*)d_in[15];
    float* out = (float*)d_out;

    char* ws = (char*)d_ws;
    float*          rr     = (float*)(ws + WS_RR);
    float*          sup    = (float*)(ws + WS_SUP);
    float*          psum   = (float*)(ws + WS_PSUM);
    float*          psumsq = (float*)(ws + WS_PSUMSQ);
    unsigned char*  W1p    = (unsigned char*)(ws + WS_W1P);
    unsigned char*  W2p    = (unsigned char*)(ws + WS_W2P);
    unsigned char*  H1buf  = (unsigned char*)(ws + WS_H1);
    float*          s1_ws  = (float*)(ws + WS_S1);
    float*          nrm_ws = (float*)(ws + WS_NRM);

    init_kernel<<<dim3(64), dim3(256), 0, stream>>>(
        dur, mask, conv1_w, conv2_w, W1p, W2p, H1buf, rr, sup, psum, out);
    conv1g_kernel<<<dim3(32, 32), dim3(256), 0, stream>>>(
        unit_ids, rr, emb, aux_w, aux_b, W1p, conv1_b, H1buf);
    conv2ln_kernel<<<dim3(64, 32), dim3(256), 0, stream>>>(
        H1buf, W2p, conv2_b, ln_g, ln_b, mask, psum, psumsq);
    mlp1_kernel<<<dim3(32, 4), dim3(128), 0, stream>>>(
        psum, psumsq, sup, p1_w, p1_b, s1_ws, nrm_ws);
    mlp2_kernel<<<dim3(32, 4), dim3(128), 0, stream>>>(
        s1_ws, sup, p2_w, p2_b, nrm_ws, out);
    mlp3_kernel<<<dim3(1), dim3(64), 0, stream>>>(nrm_ws, out);
}